// Round 6
// baseline (856.587 us; speedup 1.0000x reference)
//
#include <hip/hip_runtime.h>

#define N_NODES 100000
#define N_EDGES 1600000
#define D 64

#define BN 128                              // nodes per bucket (32 KB LDS tile)
#define NBUCK ((N_NODES + BN - 1) / BN)     // 782
#define HW 128                              // histogram/scatter chunks
#define HCH ((N_EDGES + HW - 1) / HW)       // 12500 edges per chunk
#define HLEN (NBUCK * HW)                   // 100096
#define NB1 98                              // ceil(HLEN/1024)

static __device__ __forceinline__ unsigned short f2bf(float f) {
    unsigned u = __float_as_uint(f);
    u += 0x7FFFu + ((u >> 16) & 1u);
    return (unsigned short)(u >> 16);
}
static __device__ __forceinline__ float bf2f(unsigned short h) {
    return __uint_as_float((unsigned)h << 16);
}

// ---------------- GEMM: support(bf16) = X @ W ----------------
__global__ __launch_bounds__(256) void gcn_gemm(const float* __restrict__ x,
                                                const float* __restrict__ w,
                                                unsigned short* __restrict__ support) {
    __shared__ float4 wsh[64 * 16];
    int tid = threadIdx.x;
    const float4* w4 = (const float4*)w;
    for (int i = tid; i < 64 * 16; i += 256) wsh[i] = w4[i];
    __syncthreads();

    int idx = blockIdx.x * 256 + tid;
    int rowpair = idx >> 4;
    int c4 = idx & 15;
    long r0 = (long)rowpair * 2;
    const float4* xr0 = (const float4*)(x + r0 * D);
    const float4* xr1 = (const float4*)(x + (r0 + 1) * D);

    float4 a0 = make_float4(0.f, 0.f, 0.f, 0.f);
    float4 a1 = make_float4(0.f, 0.f, 0.f, 0.f);
    #pragma unroll 4
    for (int k4 = 0; k4 < 16; ++k4) {
        float4 xv0 = xr0[k4];
        float4 xv1 = xr1[k4];
        float4 w0 = wsh[(4 * k4 + 0) * 16 + c4];
        float4 w1 = wsh[(4 * k4 + 1) * 16 + c4];
        float4 w2 = wsh[(4 * k4 + 2) * 16 + c4];
        float4 w3 = wsh[(4 * k4 + 3) * 16 + c4];
        a0 += w0 * xv0.x + w1 * xv0.y + w2 * xv0.z + w3 * xv0.w;
        a1 += w0 * xv1.x + w1 * xv1.y + w2 * xv1.z + w3 * xv1.w;
    }
    ushort4* s4 = (ushort4*)support;
    s4[r0 * 16 + c4] = make_ushort4(f2bf(a0.x), f2bf(a0.y), f2bf(a0.z), f2bf(a0.w));
    s4[(r0 + 1) * 16 + c4] = make_ushort4(f2bf(a1.x), f2bf(a1.y), f2bf(a1.z), f2bf(a1.w));
}

// ---------------- per-chunk histogram over buckets ----------------
__global__ __launch_bounds__(256) void gcn_hist(const int* __restrict__ dst,
                                                int* __restrict__ hist) {
    __shared__ int h[NBUCK];
    int tid = threadIdx.x;
    for (int i = tid; i < NBUCK; i += 256) h[i] = 0;
    __syncthreads();
    int w = blockIdx.x;
    int e0 = w * HCH, e1 = min(e0 + HCH, N_EDGES);
    for (int e = e0 + tid; e < e1; e += 256) {
        int d = __builtin_nontemporal_load(&dst[e]);
        atomicAdd(&h[d >> 7], 1);
    }
    __syncthreads();
    for (int c = tid; c < NBUCK; c += 256) hist[c * HW + w] = h[c];
}

// ---------------- exclusive scan of hist (length HLEN) ----------------
#define SCAN_B 1024
__global__ __launch_bounds__(256) void gcn_scan1(const int* __restrict__ in,
                                                 int* __restrict__ outp,
                                                 int* __restrict__ bsums, int len) {
    __shared__ int sh[256];
    int tid = threadIdx.x;
    int base = blockIdx.x * SCAN_B + tid * 4;
    int v0 = (base + 0 < len) ? in[base + 0] : 0;
    int v1 = (base + 1 < len) ? in[base + 1] : 0;
    int v2 = (base + 2 < len) ? in[base + 2] : 0;
    int v3 = (base + 3 < len) ? in[base + 3] : 0;
    int local = v0 + v1 + v2 + v3;
    sh[tid] = local;
    __syncthreads();
    for (int off = 1; off < 256; off <<= 1) {
        int t = 0;
        if (tid >= off) t = sh[tid - off];
        __syncthreads();
        if (tid >= off) sh[tid] += t;
        __syncthreads();
    }
    int excl = sh[tid] - local;
    if (base + 0 < len) outp[base + 0] = excl;
    if (base + 1 < len) outp[base + 1] = excl + v0;
    if (base + 2 < len) outp[base + 2] = excl + v0 + v1;
    if (base + 3 < len) outp[base + 3] = excl + v0 + v1 + v2;
    if (tid == 255) bsums[blockIdx.x] = sh[255];
}

__global__ __launch_bounds__(128) void gcn_scan2(int* __restrict__ bsums) {
    __shared__ int sh[128];
    int tid = threadIdx.x;
    int orig = (tid < NB1) ? bsums[tid] : 0;
    sh[tid] = orig;
    __syncthreads();
    for (int off = 1; off < 128; off <<= 1) {
        int t = 0;
        if (tid >= off) t = sh[tid - off];
        __syncthreads();
        if (tid >= off) sh[tid] += t;
        __syncthreads();
    }
    if (tid < NB1) bsums[tid] = sh[tid] - orig;  // exclusive
}

__global__ __launch_bounds__(256) void gcn_scan3(int* __restrict__ data,
                                                 const int* __restrict__ bsums, int len) {
    int i = blockIdx.x * 256 + threadIdx.x;
    if (i < len) data[i] += bsums[i >> 10];
}

// ---------------- coarse scatter: bucket-sorted edges ----------------
// base[c*HW + w] = start position for chunk w's edges of bucket c.
// (block,bucket) runs are ~16 contiguous edges -> near-line-granular writes.
__global__ __launch_bounds__(256) void gcn_coarse(const int* __restrict__ src,
                                                  const int* __restrict__ dst,
                                                  const float* __restrict__ adj,
                                                  const int* __restrict__ base,
                                                  int2* __restrict__ coarse) {
    __shared__ int cur[NBUCK];
    int tid = threadIdx.x;
    int w = blockIdx.x;
    for (int c = tid; c < NBUCK; c += 256) cur[c] = base[c * HW + w];
    __syncthreads();
    int e0 = w * HCH, e1 = min(e0 + HCH, N_EDGES);
    for (int e = e0 + tid; e < e1; e += 256) {
        int d = __builtin_nontemporal_load(&dst[e]);
        int s = __builtin_nontemporal_load(&src[e]);
        float a = __builtin_nontemporal_load(&adj[e]);
        int pos = atomicAdd(&cur[d >> 7], 1);
        coarse[pos] = make_int2(s | ((d & 127) << 17), __float_as_int(a));
    }
}

// ---------------- bucket accumulate: one block per 128-node bucket ----------------
__global__ __launch_bounds__(256) void gcn_bacc(const unsigned short* __restrict__ support,
                                                const long long* __restrict__ coarse,
                                                const int* __restrict__ base,
                                                const float* __restrict__ bias,
                                                float* __restrict__ out) {
    __shared__ float4 acc4[BN * D / 4];      // 32 KB
    __shared__ int2 eL[4][64];
    float* acc = (float*)acc4;
    int tid = threadIdx.x, wv = tid >> 6, lane = tid & 63;
    int b = blockIdx.x;

    for (int i = tid; i < BN * D / 4; i += 256)
        acc4[i] = make_float4(0.f, 0.f, 0.f, 0.f);
    __syncthreads();

    int e0 = base[b * HW];
    int e1 = (b == NBUCK - 1) ? N_EDGES : base[(b + 1) * HW];

    for (int c = e0 + wv * 64; c < e1; c += 256) {
        int rem = min(64, e1 - c);
        if (lane < rem) {
            long long p = __builtin_nontemporal_load(&coarse[c + lane]);
            eL[wv][lane] = make_int2((int)(p & 0xFFFFFFFFll), (int)(p >> 32));
        }
        __builtin_amdgcn_wave_barrier();
        int j = 0;
        for (; j + 8 <= rem; j += 8) {
            float v[8]; int nl[8];
            #pragma unroll
            for (int k = 0; k < 8; ++k) {
                int2 ed = eL[wv][j + k];
                int s = ed.x & 0x1FFFF;
                nl[k] = (ed.x >> 17) & 127;
                v[k] = __int_as_float(ed.y) * bf2f(support[(long)s * D + lane]);
            }
            #pragma unroll
            for (int k = 0; k < 8; ++k)
                atomicAdd(&acc[nl[k] * D + lane], v[k]);
        }
        for (; j < rem; ++j) {
            int2 ed = eL[wv][j];
            int s = ed.x & 0x1FFFF;
            int nl = (ed.x >> 17) & 127;
            atomicAdd(&acc[nl * D + lane],
                      __int_as_float(ed.y) * bf2f(support[(long)s * D + lane]));
        }
        __builtin_amdgcn_wave_barrier();
    }
    __syncthreads();

    int n0 = b * BN;
    const float4* bias4 = (const float4*)bias;
    float4* out4 = (float4*)out;
    for (int i = tid; i < BN * D / 4; i += 256) {
        int node = n0 + (i >> 4);
        if (node < N_NODES) {
            float4 a = acc4[i];
            float4 bv = bias4[i & 15];
            a.x += bv.x; a.y += bv.y; a.z += bv.z; a.w += bv.w;
            out4[(long)node * 16 + (i & 15)] = a;
        }
    }
}

extern "C" void kernel_launch(void* const* d_in, const int* in_sizes, int n_in,
                              void* d_out, int out_size, void* d_ws, size_t ws_size,
                              hipStream_t stream) {
    const float* x      = (const float*)d_in[0];
    const float* weight = (const float*)d_in[1];
    const float* bias   = (const float*)d_in[2];
    const float* adj    = (const float*)d_in[3];
    const int*   src    = (const int*)d_in[4];
    const int*   dst    = (const int*)d_in[5];
    float* out = (float*)d_out;

    unsigned short* support = (unsigned short*)d_ws;     // 12,800,000 B
    int2* coarse = (int2*)(support + (long)N_NODES * D); // 12,800,000 B
    int*  hist   = (int*)(coarse + N_EDGES);             // 400,384 B
    int*  scanned= hist + HLEN;                          // 400,384 B
    int*  bsums  = scanned + HLEN;                       // 512 B

    hipLaunchKernelGGL(gcn_gemm, dim3(N_NODES * 16 / 2 / 256), dim3(256), 0, stream,
                       x, weight, support);
    hipLaunchKernelGGL(gcn_hist, dim3(HW), dim3(256), 0, stream, dst, hist);
    hipLaunchKernelGGL(gcn_scan1, dim3(NB1), dim3(256), 0, stream,
                       hist, scanned, bsums, HLEN);
    hipLaunchKernelGGL(gcn_scan2, dim3(1), dim3(128), 0, stream, bsums);
    hipLaunchKernelGGL(gcn_scan3, dim3((HLEN + 255) / 256), dim3(256), 0, stream,
                       scanned, bsums, HLEN);
    hipLaunchKernelGGL(gcn_coarse, dim3(HW), dim3(256), 0, stream,
                       src, dst, adj, scanned, (int2*)coarse);
    hipLaunchKernelGGL(gcn_bacc, dim3(NBUCK), dim3(256), 0, stream,
                       support, (const long long*)coarse, scanned, bias, out);
}

// Round 7
// 226.673 us; speedup vs baseline: 3.7790x; 3.7790x over previous
//
#include <hip/hip_runtime.h>

#define N_NODES 100000
#define N_EDGES 1600000
#define D 64

#define BN 128                              // nodes per bucket
#define NBUCK ((N_NODES + BN - 1) / BN)     // 782
#define HW 256                              // histogram/scatter chunks
#define HCH ((N_EDGES + HW - 1) / HW)       // 6250 edges per chunk
#define HLEN (NBUCK * HW)                   // 200192
#define NB1 196                             // ceil(HLEN/1024)

static __device__ __forceinline__ unsigned short f2bf(float f) {
    unsigned u = __float_as_uint(f);
    u += 0x7FFFu + ((u >> 16) & 1u);
    return (unsigned short)(u >> 16);
}
static __device__ __forceinline__ float bf2f(unsigned short h) {
    return __uint_as_float((unsigned)h << 16);
}

// ---------------- GEMM: support(bf16) = X @ W ----------------
__global__ __launch_bounds__(256) void gcn_gemm(const float* __restrict__ x,
                                                const float* __restrict__ w,
                                                unsigned short* __restrict__ support) {
    __shared__ float4 wsh[64 * 16];
    int tid = threadIdx.x;
    const float4* w4 = (const float4*)w;
    for (int i = tid; i < 64 * 16; i += 256) wsh[i] = w4[i];
    __syncthreads();

    int idx = blockIdx.x * 256 + tid;
    int rowpair = idx >> 4;
    int c4 = idx & 15;
    long r0 = (long)rowpair * 2;
    const float4* xr0 = (const float4*)(x + r0 * D);
    const float4* xr1 = (const float4*)(x + (r0 + 1) * D);

    float4 a0 = make_float4(0.f, 0.f, 0.f, 0.f);
    float4 a1 = make_float4(0.f, 0.f, 0.f, 0.f);
    #pragma unroll 4
    for (int k4 = 0; k4 < 16; ++k4) {
        float4 xv0 = xr0[k4];
        float4 xv1 = xr1[k4];
        float4 w0 = wsh[(4 * k4 + 0) * 16 + c4];
        float4 w1 = wsh[(4 * k4 + 1) * 16 + c4];
        float4 w2 = wsh[(4 * k4 + 2) * 16 + c4];
        float4 w3 = wsh[(4 * k4 + 3) * 16 + c4];
        a0 += w0 * xv0.x + w1 * xv0.y + w2 * xv0.z + w3 * xv0.w;
        a1 += w0 * xv1.x + w1 * xv1.y + w2 * xv1.z + w3 * xv1.w;
    }
    ushort4* s4 = (ushort4*)support;
    s4[r0 * 16 + c4] = make_ushort4(f2bf(a0.x), f2bf(a0.y), f2bf(a0.z), f2bf(a0.w));
    s4[(r0 + 1) * 16 + c4] = make_ushort4(f2bf(a1.x), f2bf(a1.y), f2bf(a1.z), f2bf(a1.w));
}

// ---------------- per-chunk histogram over buckets (int LDS atomics) ----------------
__global__ __launch_bounds__(256) void gcn_hist(const int* __restrict__ dst,
                                                int* __restrict__ hist) {
    __shared__ int h[NBUCK];
    int tid = threadIdx.x;
    for (int i = tid; i < NBUCK; i += 256) h[i] = 0;
    __syncthreads();
    int w = blockIdx.x;
    int e0 = w * HCH, e1 = min(e0 + HCH, N_EDGES);
    for (int e = e0 + tid; e < e1; e += 256) {
        int d = __builtin_nontemporal_load(&dst[e]);
        atomicAdd(&h[d >> 7], 1);
    }
    __syncthreads();
    for (int c = tid; c < NBUCK; c += 256) hist[c * HW + w] = h[c];
}

// ---------------- exclusive scan of hist (length HLEN) ----------------
#define SCAN_B 1024
__global__ __launch_bounds__(256) void gcn_scan1(const int* __restrict__ in,
                                                 int* __restrict__ outp,
                                                 int* __restrict__ bsums, int len) {
    __shared__ int sh[256];
    int tid = threadIdx.x;
    int base = blockIdx.x * SCAN_B + tid * 4;
    int v0 = (base + 0 < len) ? in[base + 0] : 0;
    int v1 = (base + 1 < len) ? in[base + 1] : 0;
    int v2 = (base + 2 < len) ? in[base + 2] : 0;
    int v3 = (base + 3 < len) ? in[base + 3] : 0;
    int local = v0 + v1 + v2 + v3;
    sh[tid] = local;
    __syncthreads();
    for (int off = 1; off < 256; off <<= 1) {
        int t = 0;
        if (tid >= off) t = sh[tid - off];
        __syncthreads();
        if (tid >= off) sh[tid] += t;
        __syncthreads();
    }
    int excl = sh[tid] - local;
    if (base + 0 < len) outp[base + 0] = excl;
    if (base + 1 < len) outp[base + 1] = excl + v0;
    if (base + 2 < len) outp[base + 2] = excl + v0 + v1;
    if (base + 3 < len) outp[base + 3] = excl + v0 + v1 + v2;
    if (tid == 255) bsums[blockIdx.x] = sh[255];
}

__global__ __launch_bounds__(256) void gcn_scan2(int* __restrict__ bsums) {
    __shared__ int sh[256];
    int tid = threadIdx.x;
    int orig = (tid < NB1) ? bsums[tid] : 0;
    sh[tid] = orig;
    __syncthreads();
    for (int off = 1; off < 256; off <<= 1) {
        int t = 0;
        if (tid >= off) t = sh[tid - off];
        __syncthreads();
        if (tid >= off) sh[tid] += t;
        __syncthreads();
    }
    if (tid < NB1) bsums[tid] = sh[tid] - orig;  // exclusive
}

__global__ __launch_bounds__(256) void gcn_scan3(int* __restrict__ data,
                                                 const int* __restrict__ bsums, int len) {
    int i = blockIdx.x * 256 + threadIdx.x;
    if (i < len) data[i] += bsums[i >> 10];
}

// ---------------- coarse scatter: bucket-sorted edges (runs ~8 -> line-granular) ----------------
__global__ __launch_bounds__(256) void gcn_coarse(const int* __restrict__ src,
                                                  const int* __restrict__ dst,
                                                  const float* __restrict__ adj,
                                                  const int* __restrict__ base,
                                                  int2* __restrict__ coarse) {
    __shared__ int cur[NBUCK];
    int tid = threadIdx.x;
    int w = blockIdx.x;
    for (int c = tid; c < NBUCK; c += 256) cur[c] = base[c * HW + w];
    __syncthreads();
    int e0 = w * HCH, e1 = min(e0 + HCH, N_EDGES);
    for (int e = e0 + tid; e < e1; e += 256) {
        int d = __builtin_nontemporal_load(&dst[e]);
        int s = __builtin_nontemporal_load(&src[e]);
        float a = __builtin_nontemporal_load(&adj[e]);
        int pos = atomicAdd(&cur[d >> 7], 1);
        coarse[pos] = make_int2(s | ((d & 127) << 17), __float_as_int(a));
    }
}

// ---------------- fine: per-bucket counting sort into per-node order ----------------
// Writes stay inside the bucket's contiguous ~16 KB window (L2-resident, no
// write amplification). Only int LDS atomics. Emits per-node offs/cnt.
__global__ __launch_bounds__(256) void gcn_fine(const int2* __restrict__ coarse,
                                                const int* __restrict__ base,
                                                int2* __restrict__ fine,
                                                int* __restrict__ node_offs,
                                                int* __restrict__ node_cnt) {
    __shared__ int cnt[BN];
    __shared__ int loff[BN];
    __shared__ int cur[BN];
    int tid = threadIdx.x;
    int b = blockIdx.x;
    int e0 = base[b * HW];
    int e1 = (b == NBUCK - 1) ? N_EDGES : base[(b + 1) * HW];

    if (tid < BN) cnt[tid] = 0;
    __syncthreads();
    for (int e = e0 + tid; e < e1; e += 256) {
        int nl = (coarse[e].x >> 17) & 127;
        atomicAdd(&cnt[nl], 1);
    }
    __syncthreads();
    // exclusive scan of 128 counters (Hillis-Steele in LDS)
    if (tid < BN) loff[tid] = cnt[tid];
    __syncthreads();
    for (int off = 1; off < BN; off <<= 1) {
        int t = 0;
        if (tid < BN && tid >= off) t = loff[tid - off];
        __syncthreads();
        if (tid < BN && tid >= off) loff[tid] += t;
        __syncthreads();
    }
    if (tid < BN) {
        int excl = loff[tid] - cnt[tid];
        loff[tid] = excl;
        cur[tid] = excl;
        int n = b * BN + tid;
        if (n < N_NODES) {
            node_offs[n] = e0 + excl;
            node_cnt[n]  = cnt[tid];
        }
    }
    __syncthreads();
    for (int e = e0 + tid; e < e1; e += 256) {
        int2 ed = coarse[e];
        int nl = (ed.x >> 17) & 127;
        int pos = atomicAdd(&cur[nl], 1);
        fine[e0 + pos] = ed;
    }
}

// ---------------- gather: one wave per node, register acc, ILP-8, bf16 support ----------------
__global__ __launch_bounds__(256) void gcn_gather(const unsigned short* __restrict__ support,
                                                  const long long* __restrict__ edges,
                                                  const int* __restrict__ offs,
                                                  const int* __restrict__ counts,
                                                  const float* __restrict__ bias,
                                                  float* __restrict__ out) {
    __shared__ int2 eL[4][64];
    int tid = threadIdx.x;
    int wv = tid >> 6, lane = tid & 63;
    int n = blockIdx.x * 4 + wv;
    int start = offs[n];
    int cnt = counts[n];
    float acc = bias[lane];

    for (int c = 0; c < cnt; c += 64) {
        int rem = min(64, cnt - c);
        if (lane < rem) {
            long long p = __builtin_nontemporal_load(&edges[start + c + lane]);
            eL[wv][lane] = make_int2((int)(p & 0xFFFFFFFFll), (int)(p >> 32));
        }
        __builtin_amdgcn_wave_barrier();
        int j = 0;
        for (; j + 8 <= rem; j += 8) {
            float v[8];
            #pragma unroll
            for (int k = 0; k < 8; ++k) {
                int2 ed = eL[wv][j + k];
                int s = ed.x & 0x1FFFF;
                v[k] = __int_as_float(ed.y) * bf2f(support[(long)s * D + lane]);
            }
            #pragma unroll
            for (int k = 0; k < 8; ++k) acc += v[k];
        }
        for (; j < rem; ++j) {
            int2 ed = eL[wv][j];
            int s = ed.x & 0x1FFFF;
            acc += __int_as_float(ed.y) * bf2f(support[(long)s * D + lane]);
        }
        __builtin_amdgcn_wave_barrier();
    }
    __builtin_nontemporal_store(acc, &out[(long)n * D + lane]);
}

extern "C" void kernel_launch(void* const* d_in, const int* in_sizes, int n_in,
                              void* d_out, int out_size, void* d_ws, size_t ws_size,
                              hipStream_t stream) {
    const float* x      = (const float*)d_in[0];
    const float* weight = (const float*)d_in[1];
    const float* bias   = (const float*)d_in[2];
    const float* adj    = (const float*)d_in[3];
    const int*   src    = (const int*)d_in[4];
    const int*   dst    = (const int*)d_in[5];
    float* out = (float*)d_out;

    unsigned short* support = (unsigned short*)d_ws;       // 12,800,000 B
    int2* coarse  = (int2*)(support + (long)N_NODES * D);  // 12,800,000 B
    int2* fine    = coarse + N_EDGES;                      // 12,800,000 B
    int*  hist    = (int*)(fine + N_EDGES);                // 800,768 B
    int*  scanned = hist + HLEN;                           // 800,768 B
    int*  node_offs = scanned + HLEN;                      // 400,000 B
    int*  node_cnt  = node_offs + N_NODES;                 // 400,000 B
    int*  bsums     = node_cnt + N_NODES;                  // 1024 B

    hipLaunchKernelGGL(gcn_gemm, dim3(N_NODES * 16 / 2 / 256), dim3(256), 0, stream,
                       x, weight, support);
    hipLaunchKernelGGL(gcn_hist, dim3(HW), dim3(256), 0, stream, dst, hist);
    hipLaunchKernelGGL(gcn_scan1, dim3(NB1), dim3(256), 0, stream,
                       hist, scanned, bsums, HLEN);
    hipLaunchKernelGGL(gcn_scan2, dim3(1), dim3(256), 0, stream, bsums);
    hipLaunchKernelGGL(gcn_scan3, dim3((HLEN + 255) / 256), dim3(256), 0, stream,
                       scanned, bsums, HLEN);
    hipLaunchKernelGGL(gcn_coarse, dim3(HW), dim3(256), 0, stream,
                       src, dst, adj, scanned, coarse);
    hipLaunchKernelGGL(gcn_fine, dim3(NBUCK), dim3(256), 0, stream,
                       coarse, scanned, fine, node_offs, node_cnt);
    hipLaunchKernelGGL(gcn_gather, dim3(N_NODES / 4), dim3(256), 0, stream,
                       support, (const long long*)fine, node_offs, node_cnt, bias, out);
}